// Round 8
// baseline (76.742 us; speedup 1.0000x reference)
//
#include <hip/hip_runtime.h>
#include <hip/hip_bf16.h>

// Bundle-adjustment residual.
// R8: attack gather-LATENCY SERIALIZATION. Prior rounds issued gathers in
// 4-obs chunks and fully drained each chunk (vmcnt->0) before issuing the
// next -> ~40 in-flight gathers/CU (Little's law from R7 counters). Now:
//   phase 1: load all 8 obs indices (NT streams)
//   phase 2: issue ALL 8 patch4 gathers back-to-back (independent)
//   phase 3: load all targets/weights (NT)
//   phase 4: compute obs 0..7 IN ISSUE ORDER (incremental vmcnt waits keep
//            later gathers in flight during obs-0 compute), store NT.
// Substrate = best-measured combo (R5/R6): packed patch4 table in ws
// (1 gather line/obs, L2-resident), poses in LDS via coalesced linear copy,
// NT on all pure streams so they don't evict the patch table from L2.
// Quat normalization folded: rot = pts + (2/|q|^2)(qw*uv + qv x uv).

#define NPOSES      4096
#define NPATCHES    262144
#define POSE_DWORDS (NPOSES * 7)          // 28672 dwords = 112 KB
#define POSE_VEC4   (POSE_DWORDS / 4)     // 7168 float4

typedef float fvec4 __attribute__((ext_vector_type(4)));
typedef int   ivec4 __attribute__((ext_vector_type(4)));

__global__ __launch_bounds__(256) void pack_patches_kernel(
    const float* __restrict__ patch_coords, const float* __restrict__ elev,
    fvec4* __restrict__ patch4, int n)
{
    int i = blockIdx.x * blockDim.x + threadIdx.x;
    if (i >= n) return;
    float2 pc = *reinterpret_cast<const float2*>(patch_coords + (size_t)i * 2);
    patch4[i] = (fvec4){pc.x, pc.y, elev[i], 0.0f};
}

__global__ __launch_bounds__(1024) void ba_main_kernel(
    const float* __restrict__ poses,    // [4096,7] raw
    const fvec4* __restrict__ patch4,   // [NPATCHES] packed (x,y,elev,0)
    const int*   __restrict__ poses_idx,
    const int*   __restrict__ patch_idx,
    const float* __restrict__ target,   // [NOBS,3]
    const float* __restrict__ weights,  // [NOBS,1]
    float*       __restrict__ out,      // [NOBS,3]
    int n8)                             // NOBS/8
{
    extern __shared__ float lds[];      // 112 KB raw poses
    int tid = threadIdx.x;

    // Coalesced linear staging: 7168 float4 / 1024 threads = 7 each.
    {
        const fvec4* src = reinterpret_cast<const fvec4*>(poses);
        fvec4* dst = reinterpret_cast<fvec4*>(lds);
#pragma unroll
        for (int j = 0; j < POSE_VEC4 / 1024; ++j)
            dst[tid + j * 1024] = src[tid + j * 1024];
    }
    __syncthreads();

    int i8 = blockIdx.x * blockDim.x + tid;
    if (i8 >= n8) return;

    // ---- phase 1: all indices (NT streams) ----
    const ivec4* pi4 = reinterpret_cast<const ivec4*>(poses_idx) + (size_t)i8 * 2;
    const ivec4* qi4 = reinterpret_cast<const ivec4*>(patch_idx) + (size_t)i8 * 2;
    ivec4 p0 = __builtin_nontemporal_load(pi4 + 0);
    ivec4 p1 = __builtin_nontemporal_load(pi4 + 1);
    ivec4 q0 = __builtin_nontemporal_load(qi4 + 0);
    ivec4 q1 = __builtin_nontemporal_load(qi4 + 1);
    int pi[8] = {p0.x, p0.y, p0.z, p0.w, p1.x, p1.y, p1.z, p1.w};
    int qi[8] = {q0.x, q0.y, q0.z, q0.w, q1.x, q1.y, q1.z, q1.w};

    // ---- phase 2: issue ALL 8 patch gathers (plain loads, L2-resident) ----
    fvec4 pp[8];
#pragma unroll
    for (int k = 0; k < 8; ++k)
        pp[k] = patch4[qi[k]];

    // ---- phase 3: streaming targets + weights (NT) ----
    const fvec4* w4p = reinterpret_cast<const fvec4*>(weights) + (size_t)i8 * 2;
    fvec4 w0 = __builtin_nontemporal_load(w4p + 0);
    fvec4 w1 = __builtin_nontemporal_load(w4p + 1);
    const fvec4* tg4 = reinterpret_cast<const fvec4*>(target) + (size_t)i8 * 6;
    fvec4 tv[6];
#pragma unroll
    for (int j = 0; j < 6; ++j)
        tv[j] = __builtin_nontemporal_load(tg4 + j);

    float ww[8] = {w0.x, w0.y, w0.z, w0.w, w1.x, w1.y, w1.z, w1.w};
    float tg[24] = {tv[0].x, tv[0].y, tv[0].z, tv[0].w,
                    tv[1].x, tv[1].y, tv[1].z, tv[1].w,
                    tv[2].x, tv[2].y, tv[2].z, tv[2].w,
                    tv[3].x, tv[3].y, tv[3].z, tv[3].w,
                    tv[4].x, tv[4].y, tv[4].z, tv[4].w,
                    tv[5].x, tv[5].y, tv[5].z, tv[5].w};

    // ---- phase 4: compute in gather-issue order ----
    float res[24];
#pragma unroll
    for (int k = 0; k < 8; ++k) {
        // Pose from LDS (7 dwords, stride-7 rows spread over 32 banks).
        const float* pl = lds + pi[k] * 7;
        float tx = pl[0], ty = pl[1], tz = pl[2];
        float qx = pl[3], qy = pl[4], qz = pl[5], qw = pl[6];
        float dot  = qx*qx + qy*qy + qz*qz + qw*qw;
        float inv  = rsqrtf(dot);
        float inv2 = 2.0f * inv * inv;     // rot = pts + inv2*(qw*uv + qv x uv)

        float px = pp[k].x, py = pp[k].y, pz = pp[k].z;

        // uv = cross(qv, pts)   (unnormalized q)
        float ux = qy*pz - qz*py;
        float uy = qz*px - qx*pz;
        float uz = qx*py - qy*px;
        // cross(qv, uv)
        float cx = qy*uz - qz*uy;
        float cy = qz*ux - qx*uz;
        float cz = qx*uy - qy*ux;
        float rx = px + inv2*(qw*ux + cx) + tx;
        float ry = py + inv2*(qw*uy + cy) + ty;
        float rz = pz + inv2*(qw*uz + cz) + tz;

        // cart2polar (matches reference)
        float rho = sqrtf(rx*rx + ry*ry);
        float r   = sqrtf(rho*rho + rz*rz);
        float az  = atan2f(ry, rx);
        float el  = atan2f(rz, rho);

        res[k*3 + 0] = (r  - tg[k*3 + 0]) * ww[k];
        res[k*3 + 1] = (az - tg[k*3 + 1]) * ww[k];
        res[k*3 + 2] = (el - tg[k*3 + 2]) * ww[k];
    }

    fvec4* o4 = reinterpret_cast<fvec4*>(out) + (size_t)i8 * 6;
#pragma unroll
    for (int j = 0; j < 6; ++j)
        __builtin_nontemporal_store(
            (fvec4){res[j*4 + 0], res[j*4 + 1], res[j*4 + 2], res[j*4 + 3]}, o4 + j);
}

// Fallback path: direct global gathers (no ws / no big-LDS attribute).
__global__ __launch_bounds__(256) void ba_fallback_kernel(
    const float* __restrict__ poses, const float* __restrict__ patch_coords,
    const float* __restrict__ elev, const int* __restrict__ poses_idx,
    const int* __restrict__ patch_idx, const float* __restrict__ target,
    const float* __restrict__ weights, float* __restrict__ out, int n)
{
    int i = blockIdx.x * blockDim.x + threadIdx.x;
    if (i >= n) return;
    int pi = poses_idx[i];
    int qi = patch_idx[i];
    const float* p = poses + (size_t)pi * 7;
    float tx = p[0], ty = p[1], tz = p[2];
    float qx = p[3], qy = p[4], qz = p[5], qw = p[6];
    float inv = rsqrtf(qx*qx + qy*qy + qz*qz + qw*qw);
    qx *= inv; qy *= inv; qz *= inv; qw *= inv;
    float2 pc = *reinterpret_cast<const float2*>(patch_coords + (size_t)qi * 2);
    float px = pc.x, py = pc.y, pz = elev[qi];
    float ux = qy*pz - qz*py, uy = qz*px - qx*pz, uz = qx*py - qy*px;
    float cx = qy*uz - qz*uy, cy = qz*ux - qx*uz, cz = qx*uy - qy*ux;
    float rx = px + 2.0f*(qw*ux + cx) + tx;
    float ry = py + 2.0f*(qw*uy + cy) + ty;
    float rz = pz + 2.0f*(qw*uz + cz) + tz;
    float rho = sqrtf(rx*rx + ry*ry);
    float r   = sqrtf(rho*rho + rz*rz);
    float az  = atan2f(ry, rx);
    float el  = atan2f(rz, rho);
    float w = weights[i];
    out[(size_t)i*3+0] = (r  - target[(size_t)i*3+0]) * w;
    out[(size_t)i*3+1] = (az - target[(size_t)i*3+1]) * w;
    out[(size_t)i*3+2] = (el - target[(size_t)i*3+2]) * w;
}

extern "C" void kernel_launch(void* const* d_in, const int* in_sizes, int n_in,
                              void* d_out, int out_size, void* d_ws, size_t ws_size,
                              hipStream_t stream) {
    const float* poses        = (const float*)d_in[0];
    const float* patch_coords = (const float*)d_in[1];
    const float* elev         = (const float*)d_in[2];
    const int*   poses_idx    = (const int*)d_in[3];
    const int*   patch_idx    = (const int*)d_in[4];
    const float* target       = (const float*)d_in[5];
    const float* weights      = (const float*)d_in[6];
    float*       out          = (float*)d_out;

    int n  = in_sizes[3];  // NUM_OBS (2097152, divisible by 8)
    int n8 = n / 8;

    size_t patch_bytes = (size_t)NPATCHES * 16;   // 4 MiB
    size_t lds_bytes   = (size_t)POSE_DWORDS * 4; // 114688 B

    hipError_t attr_err = hipFuncSetAttribute(
        reinterpret_cast<const void*>(ba_main_kernel),
        hipFuncAttributeMaxDynamicSharedMemorySize, (int)lds_bytes);

    if (attr_err == hipSuccess && ws_size >= patch_bytes) {
        fvec4* patch4 = (fvec4*)d_ws;
        pack_patches_kernel<<<(NPATCHES + 255) / 256, 256, 0, stream>>>(
            patch_coords, elev, patch4, NPATCHES);

        int block = 1024;
        int grid  = (n8 + block - 1) / block;  // 256 = one block per CU
        ba_main_kernel<<<grid, block, lds_bytes, stream>>>(
            poses, patch4, poses_idx, patch_idx, target, weights, out, n8);
    } else {
        ba_fallback_kernel<<<(n + 255) / 256, 256, 0, stream>>>(
            poses, patch_coords, elev, poses_idx, patch_idx, target, weights, out, n);
    }
}

// Round 9
// 73.150 us; speedup vs baseline: 1.0491x; 1.0491x over previous
//
#include <hip/hip_runtime.h>
#include <hip/hip_bf16.h>

// Bundle-adjustment residual.
// R9 = R8 batch-issue structure, fixed:
//  (1) __launch_bounds__(1024, 4): dynamic-LDS kernels hide the 1-block/CU
//      occupancy from the compiler; R8 got a 2-block/CU VGPR budget (48) and
//      spilled all batched state to scratch (WRITE 60MB). min-4-waves/EU
//      declares exactly our occupancy -> 128 VGPR budget, no spills.
//  (2) patch gathers use global_load_dwordx4 sc0 (L1-bypass): a 4MB table
//      can never live in 32KB L1, so every obs was paying a 128B line fill
//      for 16 used bytes. sc0 serves 16B straight from L2.
//      Pattern per guide rule 18: asm loads -> s_waitcnt vmcnt(0) ->
//      sched_barrier(0) so consumers can't hoist above the wait.
//  (3) stores per 4-obs group to cap live registers (~90).
// Substrate kept from R5/R6 (best measured, FETCH ~ideal): poses in LDS via
// coalesced linear copy (stride-7 rows, coprime with 32 banks), packed
// patch4 table in ws, NT on all pure streams.

#define NPOSES      4096
#define NPATCHES    262144
#define POSE_DWORDS (NPOSES * 7)          // 28672 dwords = 112 KB
#define POSE_VEC4   (POSE_DWORDS / 4)     // 7168 float4

typedef float fvec4 __attribute__((ext_vector_type(4)));
typedef int   ivec4 __attribute__((ext_vector_type(4)));

__global__ __launch_bounds__(256) void pack_patches_kernel(
    const float* __restrict__ patch_coords, const float* __restrict__ elev,
    fvec4* __restrict__ patch4, int n)
{
    int i = blockIdx.x * blockDim.x + threadIdx.x;
    if (i >= n) return;
    float2 pc = *reinterpret_cast<const float2*>(patch_coords + (size_t)i * 2);
    patch4[i] = (fvec4){pc.x, pc.y, elev[i], 0.0f};
}

__device__ __forceinline__ fvec4 gather_sc0(const fvec4* addr) {
    fvec4 v;
    asm volatile("global_load_dwordx4 %0, %1, off sc0" : "=v"(v) : "v"(addr));
    return v;
}

__global__ __launch_bounds__(1024, 4) void ba_main_kernel(
    const float* __restrict__ poses,    // [4096,7] raw
    const fvec4* __restrict__ patch4,   // [NPATCHES] packed (x,y,elev,0)
    const int*   __restrict__ poses_idx,
    const int*   __restrict__ patch_idx,
    const float* __restrict__ target,   // [NOBS,3]
    const float* __restrict__ weights,  // [NOBS,1]
    float*       __restrict__ out,      // [NOBS,3]
    int n8)                             // NOBS/8
{
    extern __shared__ float lds[];      // 112 KB raw poses
    int tid = threadIdx.x;

    // Coalesced linear staging: 7168 float4 / 1024 threads = 7 each.
    {
        const fvec4* src = reinterpret_cast<const fvec4*>(poses);
        fvec4* dst = reinterpret_cast<fvec4*>(lds);
#pragma unroll
        for (int j = 0; j < POSE_VEC4 / 1024; ++j)
            dst[tid + j * 1024] = src[tid + j * 1024];
    }
    __syncthreads();

    int i8 = blockIdx.x * blockDim.x + tid;
    if (i8 >= n8) return;

    // ---- indices (NT streams; gathers depend on them) ----
    const ivec4* pi4 = reinterpret_cast<const ivec4*>(poses_idx) + (size_t)i8 * 2;
    const ivec4* qi4 = reinterpret_cast<const ivec4*>(patch_idx) + (size_t)i8 * 2;
    ivec4 p0 = __builtin_nontemporal_load(pi4 + 0);
    ivec4 p1 = __builtin_nontemporal_load(pi4 + 1);
    ivec4 q0 = __builtin_nontemporal_load(qi4 + 0);
    ivec4 q1 = __builtin_nontemporal_load(qi4 + 1);
    int pi[8] = {p0.x, p0.y, p0.z, p0.w, p1.x, p1.y, p1.z, p1.w};

    // ---- issue ALL 8 patch gathers, L1-bypassed (sc0) ----
    fvec4 pp[8];
    {
        int qi[8] = {q0.x, q0.y, q0.z, q0.w, q1.x, q1.y, q1.z, q1.w};
#pragma unroll
        for (int k = 0; k < 8; ++k)
            pp[k] = gather_sc0(patch4 + qi[k]);
    }

    // ---- targets + weights (NT), issued while gathers are in flight ----
    const fvec4* w4p = reinterpret_cast<const fvec4*>(weights) + (size_t)i8 * 2;
    fvec4 w0 = __builtin_nontemporal_load(w4p + 0);
    fvec4 w1 = __builtin_nontemporal_load(w4p + 1);
    const fvec4* tg4 = reinterpret_cast<const fvec4*>(target) + (size_t)i8 * 6;
    fvec4 tv[6];
#pragma unroll
    for (int j = 0; j < 6; ++j)
        tv[j] = __builtin_nontemporal_load(tg4 + j);

    // Drain all VMEM (asm gathers + NT loads), then fence the scheduler so
    // no consumer of pp[] hoists above the wait (guide rule 18).
    asm volatile("s_waitcnt vmcnt(0)" ::: "memory");
    __builtin_amdgcn_sched_barrier(0);

    float ww[8] = {w0.x, w0.y, w0.z, w0.w, w1.x, w1.y, w1.z, w1.w};
    fvec4* o4 = reinterpret_cast<fvec4*>(out) + (size_t)i8 * 6;

#pragma unroll
    for (int g = 0; g < 2; ++g) {
        float res[12];
        float tg[12] = {tv[g*3+0].x, tv[g*3+0].y, tv[g*3+0].z, tv[g*3+0].w,
                        tv[g*3+1].x, tv[g*3+1].y, tv[g*3+1].z, tv[g*3+1].w,
                        tv[g*3+2].x, tv[g*3+2].y, tv[g*3+2].z, tv[g*3+2].w};
#pragma unroll
        for (int k = 0; k < 4; ++k) {
            int o = g * 4 + k;
            // Pose from LDS (7 dwords, stride-7 rows spread over 32 banks).
            const float* pl = lds + pi[o] * 7;
            float tx = pl[0], ty = pl[1], tz = pl[2];
            float qx = pl[3], qy = pl[4], qz = pl[5], qw = pl[6];
            float dot  = qx*qx + qy*qy + qz*qz + qw*qw;
            float inv2 = 2.0f / dot;   // rot = pts + inv2*(qw*uv + qv x uv)

            float px = pp[o].x, py = pp[o].y, pz = pp[o].z;

            // uv = cross(qv, pts)   (unnormalized q)
            float ux = qy*pz - qz*py;
            float uy = qz*px - qx*pz;
            float uz = qx*py - qy*px;
            // cross(qv, uv)
            float cx = qy*uz - qz*uy;
            float cy = qz*ux - qx*uz;
            float cz = qx*uy - qy*ux;
            float rx = px + inv2*(qw*ux + cx) + tx;
            float ry = py + inv2*(qw*uy + cy) + ty;
            float rz = pz + inv2*(qw*uz + cz) + tz;

            // cart2polar (matches reference)
            float rho = sqrtf(rx*rx + ry*ry);
            float r   = sqrtf(rho*rho + rz*rz);
            float az  = atan2f(ry, rx);
            float el  = atan2f(rz, rho);

            res[k*3 + 0] = (r  - tg[k*3 + 0]) * ww[o];
            res[k*3 + 1] = (az - tg[k*3 + 1]) * ww[o];
            res[k*3 + 2] = (el - tg[k*3 + 2]) * ww[o];
        }
#pragma unroll
        for (int j = 0; j < 3; ++j)
            __builtin_nontemporal_store(
                (fvec4){res[j*4+0], res[j*4+1], res[j*4+2], res[j*4+3]},
                o4 + g*3 + j);
    }
}

// Fallback path: direct global gathers (no ws / no big-LDS attribute).
__global__ __launch_bounds__(256) void ba_fallback_kernel(
    const float* __restrict__ poses, const float* __restrict__ patch_coords,
    const float* __restrict__ elev, const int* __restrict__ poses_idx,
    const int* __restrict__ patch_idx, const float* __restrict__ target,
    const float* __restrict__ weights, float* __restrict__ out, int n)
{
    int i = blockIdx.x * blockDim.x + threadIdx.x;
    if (i >= n) return;
    int pi = poses_idx[i];
    int qi = patch_idx[i];
    const float* p = poses + (size_t)pi * 7;
    float tx = p[0], ty = p[1], tz = p[2];
    float qx = p[3], qy = p[4], qz = p[5], qw = p[6];
    float inv = rsqrtf(qx*qx + qy*qy + qz*qz + qw*qw);
    qx *= inv; qy *= inv; qz *= inv; qw *= inv;
    float2 pc = *reinterpret_cast<const float2*>(patch_coords + (size_t)qi * 2);
    float px = pc.x, py = pc.y, pz = elev[qi];
    float ux = qy*pz - qz*py, uy = qz*px - qx*pz, uz = qx*py - qy*px;
    float cx = qy*uz - qz*uy, cy = qz*ux - qx*uz, cz = qx*uy - qy*ux;
    float rx = px + 2.0f*(qw*ux + cx) + tx;
    float ry = py + 2.0f*(qw*uy + cy) + ty;
    float rz = pz + 2.0f*(qw*uz + cz) + tz;
    float rho = sqrtf(rx*rx + ry*ry);
    float r   = sqrtf(rho*rho + rz*rz);
    float az  = atan2f(ry, rx);
    float el  = atan2f(rz, rho);
    float w = weights[i];
    out[(size_t)i*3+0] = (r  - target[(size_t)i*3+0]) * w;
    out[(size_t)i*3+1] = (az - target[(size_t)i*3+1]) * w;
    out[(size_t)i*3+2] = (el - target[(size_t)i*3+2]) * w;
}

extern "C" void kernel_launch(void* const* d_in, const int* in_sizes, int n_in,
                              void* d_out, int out_size, void* d_ws, size_t ws_size,
                              hipStream_t stream) {
    const float* poses        = (const float*)d_in[0];
    const float* patch_coords = (const float*)d_in[1];
    const float* elev         = (const float*)d_in[2];
    const int*   poses_idx    = (const int*)d_in[3];
    const int*   patch_idx    = (const int*)d_in[4];
    const float* target       = (const float*)d_in[5];
    const float* weights      = (const float*)d_in[6];
    float*       out          = (float*)d_out;

    int n  = in_sizes[3];  // NUM_OBS (2097152, divisible by 8)
    int n8 = n / 8;

    size_t patch_bytes = (size_t)NPATCHES * 16;   // 4 MiB
    size_t lds_bytes   = (size_t)POSE_DWORDS * 4; // 114688 B

    hipError_t attr_err = hipFuncSetAttribute(
        reinterpret_cast<const void*>(ba_main_kernel),
        hipFuncAttributeMaxDynamicSharedMemorySize, (int)lds_bytes);

    if (attr_err == hipSuccess && ws_size >= patch_bytes) {
        fvec4* patch4 = (fvec4*)d_ws;
        pack_patches_kernel<<<(NPATCHES + 255) / 256, 256, 0, stream>>>(
            patch_coords, elev, patch4, NPATCHES);

        int block = 1024;
        int grid  = (n8 + block - 1) / block;  // 256 = one block per CU
        ba_main_kernel<<<grid, block, lds_bytes, stream>>>(
            poses, patch4, poses_idx, patch_idx, target, weights, out, n8);
    } else {
        ba_fallback_kernel<<<(n + 255) / 256, 256, 0, stream>>>(
            poses, patch_coords, elev, poses_idx, patch_idx, target, weights, out, n);
    }
}

// Round 11
// 70.845 us; speedup vs baseline: 1.0832x; 1.0325x over previous
//
#include <hip/hip_runtime.h>
#include <hip/hip_bf16.h>

// Bundle-adjustment residual.
// R11: batch-issue concurrency, done in a compiler-friendly way.
//  - STATIC 112KB LDS (not extern/dynamic): the compiler then KNOWS the
//    kernel is 1 block/CU (4 waves/SIMD) and budgets 128 VGPR -> the 2-deep
//    pipeline state fits in registers. R8/R9 used dynamic LDS and the
//    compiler budgeted for 2 blocks/CU (48-60 VGPR) -> spilled everything
//    to scratch (WRITE_SIZE 54-60MB vs 27 ideal).
//  - 2-deep group pipeline with STATIC variable names (no arrays, no asm):
//    issue A-gathers, B-gathers, A+B streams; compute A while B's loads are
//    still in flight (compiler emits incremental vmcnt waits).
//  - Substrate from best-measured R5/R6: poses staged to LDS by coalesced
//    linear float4 copy (raw stride-7 rows, coprime with 32 banks), packed
//    patch4 table in ws (1 gather line/obs, L2-resident), NT hints on all
//    pure streams so they don't evict the patch table.
//  - All math fp32 (R10 lesson: atan2 branch cut forbids ANY input
//    quantization - fp16 patch coords flipped az by 2*pi).

#define NPOSES      4096
#define NPATCHES    262144
#define POSE_DWORDS (NPOSES * 7)          // 28672 dwords = 112 KB
#define POSE_VEC4   (POSE_DWORDS / 4)     // 7168 float4

typedef float fvec4 __attribute__((ext_vector_type(4)));
typedef int   ivec4 __attribute__((ext_vector_type(4)));

__global__ __launch_bounds__(256) void pack_patches_kernel(
    const float* __restrict__ patch_coords, const float* __restrict__ elev,
    fvec4* __restrict__ patch4, int n)
{
    int i = blockIdx.x * blockDim.x + threadIdx.x;
    if (i >= n) return;
    float2 pc = *reinterpret_cast<const float2*>(patch_coords + (size_t)i * 2);
    patch4[i] = (fvec4){pc.x, pc.y, elev[i], 0.0f};
}

// Per-observation math: pose from LDS row, patch in registers.
__device__ __forceinline__ void ba_obs(
    const float* __restrict__ lds, int pi, fvec4 pp,
    float t0, float t1, float t2, float w,
    float& r0, float& r1, float& r2)
{
    const float* pl = lds + pi * 7;
    float tx = pl[0], ty = pl[1], tz = pl[2];
    float qx = pl[3], qy = pl[4], qz = pl[5], qw = pl[6];
    float dot  = qx*qx + qy*qy + qz*qz + qw*qw;
    float inv2 = 2.0f / dot;      // rot = pts + inv2*(qw*uv + qv x uv)

    float px = pp.x, py = pp.y, pz = pp.z;

    float ux = qy*pz - qz*py;
    float uy = qz*px - qx*pz;
    float uz = qx*py - qy*px;
    float cx = qy*uz - qz*uy;
    float cy = qz*ux - qx*uz;
    float cz = qx*uy - qy*ux;
    float rx = px + inv2*(qw*ux + cx) + tx;
    float ry = py + inv2*(qw*uy + cy) + ty;
    float rz = pz + inv2*(qw*uz + cz) + tz;

    float rho = sqrtf(rx*rx + ry*ry);
    float r   = sqrtf(rho*rho + rz*rz);
    float az  = atan2f(ry, rx);
    float el  = atan2f(rz, rho);

    r0 = (r  - t0) * w;
    r1 = (az - t1) * w;
    r2 = (el - t2) * w;
}

__global__ __launch_bounds__(1024) void ba_main_kernel(
    const float* __restrict__ poses,    // [4096,7] raw
    const fvec4* __restrict__ patch4,   // [NPATCHES] packed (x,y,elev,0)
    const int*   __restrict__ poses_idx,
    const int*   __restrict__ patch_idx,
    const float* __restrict__ target,   // [NOBS,3]
    const float* __restrict__ weights,  // [NOBS,1]
    float*       __restrict__ out,      // [NOBS,3]
    int n8)                             // NOBS/8
{
    __shared__ float lds[POSE_DWORDS];  // 112 KB STATIC -> compiler knows 1 blk/CU
    int tid = threadIdx.x;

    // Coalesced linear staging: 7168 float4 / 1024 threads = 7 each.
    {
        const fvec4* src = reinterpret_cast<const fvec4*>(poses);
        fvec4* dst = reinterpret_cast<fvec4*>(lds);
#pragma unroll
        for (int j = 0; j < POSE_VEC4 / 1024; ++j)
            dst[tid + j * 1024] = src[tid + j * 1024];
    }
    __syncthreads();

    int i8 = blockIdx.x * blockDim.x + tid;
    if (i8 >= n8) return;

    const ivec4* pi4 = reinterpret_cast<const ivec4*>(poses_idx) + (size_t)i8 * 2;
    const ivec4* qi4 = reinterpret_cast<const ivec4*>(patch_idx) + (size_t)i8 * 2;
    const fvec4* w4p = reinterpret_cast<const fvec4*>(weights) + (size_t)i8 * 2;
    const fvec4* tg4 = reinterpret_cast<const fvec4*>(target) + (size_t)i8 * 6;
    fvec4*       o4  = reinterpret_cast<fvec4*>(out) + (size_t)i8 * 6;

    // ---- indices for both groups ----
    ivec4 pidxA = __builtin_nontemporal_load(pi4 + 0);
    ivec4 pidxB = __builtin_nontemporal_load(pi4 + 1);
    ivec4 qidxA = __builtin_nontemporal_load(qi4 + 0);
    ivec4 qidxB = __builtin_nontemporal_load(qi4 + 1);

    // ---- issue ALL 8 patch gathers (A then B), static names ----
    fvec4 ppA0 = patch4[qidxA.x];
    fvec4 ppA1 = patch4[qidxA.y];
    fvec4 ppA2 = patch4[qidxA.z];
    fvec4 ppA3 = patch4[qidxA.w];
    fvec4 ppB0 = patch4[qidxB.x];
    fvec4 ppB1 = patch4[qidxB.y];
    fvec4 ppB2 = patch4[qidxB.z];
    fvec4 ppB3 = patch4[qidxB.w];

    // ---- streams for both groups (NT), in flight with the gathers ----
    fvec4 wA  = __builtin_nontemporal_load(w4p + 0);
    fvec4 wB  = __builtin_nontemporal_load(w4p + 1);
    fvec4 tA0 = __builtin_nontemporal_load(tg4 + 0);
    fvec4 tA1 = __builtin_nontemporal_load(tg4 + 1);
    fvec4 tA2 = __builtin_nontemporal_load(tg4 + 2);
    fvec4 tB0 = __builtin_nontemporal_load(tg4 + 3);
    fvec4 tB1 = __builtin_nontemporal_load(tg4 + 4);
    fvec4 tB2 = __builtin_nontemporal_load(tg4 + 5);

    // ---- compute group A (B's loads still in flight) ----
    float a00, a01, a02, a10, a11, a12, a20, a21, a22, a30, a31, a32;
    ba_obs(lds, pidxA.x, ppA0, tA0.x, tA0.y, tA0.z, wA.x, a00, a01, a02);
    ba_obs(lds, pidxA.y, ppA1, tA0.w, tA1.x, tA1.y, wA.y, a10, a11, a12);
    ba_obs(lds, pidxA.z, ppA2, tA1.z, tA1.w, tA2.x, wA.z, a20, a21, a22);
    ba_obs(lds, pidxA.w, ppA3, tA2.y, tA2.z, tA2.w, wA.w, a30, a31, a32);
    __builtin_nontemporal_store((fvec4){a00, a01, a02, a10}, o4 + 0);
    __builtin_nontemporal_store((fvec4){a11, a12, a20, a21}, o4 + 1);
    __builtin_nontemporal_store((fvec4){a22, a30, a31, a32}, o4 + 2);

    // ---- compute group B ----
    float b00, b01, b02, b10, b11, b12, b20, b21, b22, b30, b31, b32;
    ba_obs(lds, pidxB.x, ppB0, tB0.x, tB0.y, tB0.z, wB.x, b00, b01, b02);
    ba_obs(lds, pidxB.y, ppB1, tB0.w, tB1.x, tB1.y, wB.y, b10, b11, b12);
    ba_obs(lds, pidxB.z, ppB2, tB1.z, tB1.w, tB2.x, wB.z, b20, b21, b22);
    ba_obs(lds, pidxB.w, ppB3, tB2.y, tB2.z, tB2.w, wB.w, b30, b31, b32);
    __builtin_nontemporal_store((fvec4){b00, b01, b02, b10}, o4 + 3);
    __builtin_nontemporal_store((fvec4){b11, b12, b20, b21}, o4 + 4);
    __builtin_nontemporal_store((fvec4){b22, b30, b31, b32}, o4 + 5);
}

// Fallback path: direct global gathers (no ws needed).
__global__ __launch_bounds__(256) void ba_fallback_kernel(
    const float* __restrict__ poses, const float* __restrict__ patch_coords,
    const float* __restrict__ elev, const int* __restrict__ poses_idx,
    const int* __restrict__ patch_idx, const float* __restrict__ target,
    const float* __restrict__ weights, float* __restrict__ out, int n)
{
    int i = blockIdx.x * blockDim.x + threadIdx.x;
    if (i >= n) return;
    int pi = poses_idx[i];
    int qi = patch_idx[i];
    const float* p = poses + (size_t)pi * 7;
    float tx = p[0], ty = p[1], tz = p[2];
    float qx = p[3], qy = p[4], qz = p[5], qw = p[6];
    float inv = rsqrtf(qx*qx + qy*qy + qz*qz + qw*qw);
    qx *= inv; qy *= inv; qz *= inv; qw *= inv;
    float2 pc = *reinterpret_cast<const float2*>(patch_coords + (size_t)qi * 2);
    float px = pc.x, py = pc.y, pz = elev[qi];
    float ux = qy*pz - qz*py, uy = qz*px - qx*pz, uz = qx*py - qy*px;
    float cx = qy*uz - qz*uy, cy = qz*ux - qx*uz, cz = qx*uy - qy*ux;
    float rx = px + 2.0f*(qw*ux + cx) + tx;
    float ry = py + 2.0f*(qw*uy + cy) + ty;
    float rz = pz + 2.0f*(qw*uz + cz) + tz;
    float rho = sqrtf(rx*rx + ry*ry);
    float r   = sqrtf(rho*rho + rz*rz);
    float az  = atan2f(ry, rx);
    float el  = atan2f(rz, rho);
    float w = weights[i];
    out[(size_t)i*3+0] = (r  - target[(size_t)i*3+0]) * w;
    out[(size_t)i*3+1] = (az - target[(size_t)i*3+1]) * w;
    out[(size_t)i*3+2] = (el - target[(size_t)i*3+2]) * w;
}

extern "C" void kernel_launch(void* const* d_in, const int* in_sizes, int n_in,
                              void* d_out, int out_size, void* d_ws, size_t ws_size,
                              hipStream_t stream) {
    const float* poses        = (const float*)d_in[0];
    const float* patch_coords = (const float*)d_in[1];
    const float* elev         = (const float*)d_in[2];
    const int*   poses_idx    = (const int*)d_in[3];
    const int*   patch_idx    = (const int*)d_in[4];
    const float* target       = (const float*)d_in[5];
    const float* weights      = (const float*)d_in[6];
    float*       out          = (float*)d_out;

    int n  = in_sizes[3];  // NUM_OBS (2097152, divisible by 8)
    int n8 = n / 8;

    size_t patch_bytes = (size_t)NPATCHES * 16;   // 4 MiB

    if (ws_size >= patch_bytes) {
        fvec4* patch4 = (fvec4*)d_ws;
        pack_patches_kernel<<<(NPATCHES + 255) / 256, 256, 0, stream>>>(
            patch_coords, elev, patch4, NPATCHES);

        int block = 1024;
        int grid  = (n8 + block - 1) / block;  // 256 = one block per CU
        ba_main_kernel<<<grid, block, 0, stream>>>(
            poses, patch4, poses_idx, patch_idx, target, weights, out, n8);
    } else {
        ba_fallback_kernel<<<(n + 255) / 256, 256, 0, stream>>>(
            poses, patch_coords, elev, poses_idx, patch_idx, target, weights, out, n);
    }
}

// Round 12
// 54.333 us; speedup vs baseline: 1.4124x; 1.3039x over previous
//
#include <hip/hip_runtime.h>
#include <hip/hip_bf16.h>

// Bundle-adjustment residual.
// R12: single-variable A/B vs the cleanest baseline (R3: 256-thr, 4 obs/thr,
// packed pose4/patch4 ws tables, VGPR 36, no spills, 47us profiled).
// ONLY change: the 12 divergent gathers use global_load_dwordx4 sc0
// (L1-bypass). Theory: tables (128KB/4MB) can't live in 32KB L1, so every
// gather was a line-fill through a small MSHR pool (128B filled, 16B used)
// -> the invariant ~45us wall across R1-R11. sc0 serves 16B from L2 with
// no fill, no MSHR-line limit. Rule-18 pattern: asm loads -> s_waitcnt
// vmcnt(0) -> sched_barrier(0) before any consumer.
// __launch_bounds__(256,4): 128-VGPR budget so 12 in-flight results don't
// spill (R8/R9/R11 lesson: spills masked every batching experiment).

#define NPOSES   4096
#define NPATCHES 262144

typedef float fvec4 __attribute__((ext_vector_type(4)));
typedef int   ivec4 __attribute__((ext_vector_type(4)));

__global__ __launch_bounds__(256) void pack_poses_kernel(
    const float* __restrict__ poses, fvec4* __restrict__ pose4, int n)
{
    int i = blockIdx.x * blockDim.x + threadIdx.x;
    if (i >= n) return;
    const float* p = poses + (size_t)i * 7;
    float tx = p[0], ty = p[1], tz = p[2];
    float qx = p[3], qy = p[4], qz = p[5], qw = p[6];
    float inv = rsqrtf(qx*qx + qy*qy + qz*qz + qw*qw);
    pose4[2*i + 0] = (fvec4){tx, ty, tz, qw * inv};
    pose4[2*i + 1] = (fvec4){qx * inv, qy * inv, qz * inv, 0.0f};
}

__global__ __launch_bounds__(256) void pack_patches_kernel(
    const float* __restrict__ patch_coords, const float* __restrict__ elev,
    fvec4* __restrict__ patch4, int n)
{
    int i = blockIdx.x * blockDim.x + threadIdx.x;
    if (i >= n) return;
    float2 pc = *reinterpret_cast<const float2*>(patch_coords + (size_t)i * 2);
    patch4[i] = (fvec4){pc.x, pc.y, elev[i], 0.0f};
}

__device__ __forceinline__ fvec4 load_sc0(const fvec4* addr) {
    fvec4 v;
    asm volatile("global_load_dwordx4 %0, %1, off sc0" : "=v"(v) : "v"(addr));
    return v;
}

__global__ __launch_bounds__(256, 4) void ba_main_kernel(
    const fvec4* __restrict__ pose4,   // [2*NPOSES] (t,qw_n | qxyz_n,0)
    const fvec4* __restrict__ patch4,  // [NPATCHES] (x,y,elev,0)
    const int*   __restrict__ poses_idx,
    const int*   __restrict__ patch_idx,
    const float* __restrict__ target,  // [NOBS,3]
    const float* __restrict__ weights, // [NOBS,1]
    float*       __restrict__ out,     // [NOBS,3]
    int n4)                            // NOBS/4
{
    int i4 = blockIdx.x * blockDim.x + threadIdx.x;
    if (i4 >= n4) return;

    // Indices first (gather addresses depend on them).
    ivec4 pidx = __builtin_nontemporal_load(reinterpret_cast<const ivec4*>(poses_idx) + i4);
    ivec4 qidx = __builtin_nontemporal_load(reinterpret_cast<const ivec4*>(patch_idx) + i4);

    // Issue ALL 12 gathers back-to-back, L1-bypassed (sc0).
    fvec4 pa0 = load_sc0(pose4 + 2*pidx.x + 0);
    fvec4 pb0 = load_sc0(pose4 + 2*pidx.x + 1);
    fvec4 pa1 = load_sc0(pose4 + 2*pidx.y + 0);
    fvec4 pb1 = load_sc0(pose4 + 2*pidx.y + 1);
    fvec4 pa2 = load_sc0(pose4 + 2*pidx.z + 0);
    fvec4 pb2 = load_sc0(pose4 + 2*pidx.z + 1);
    fvec4 pa3 = load_sc0(pose4 + 2*pidx.w + 0);
    fvec4 pb3 = load_sc0(pose4 + 2*pidx.w + 1);
    fvec4 pp0 = load_sc0(patch4 + qidx.x);
    fvec4 pp1 = load_sc0(patch4 + qidx.y);
    fvec4 pp2 = load_sc0(patch4 + qidx.z);
    fvec4 pp3 = load_sc0(patch4 + qidx.w);

    // Streams (NT: evict-first, keep tables L2-resident), in flight with gathers.
    fvec4 w4 = __builtin_nontemporal_load(reinterpret_cast<const fvec4*>(weights) + i4);
    const fvec4* tg4 = reinterpret_cast<const fvec4*>(target) + (size_t)i4 * 3;
    fvec4 t0 = __builtin_nontemporal_load(tg4 + 0);
    fvec4 t1 = __builtin_nontemporal_load(tg4 + 1);
    fvec4 t2 = __builtin_nontemporal_load(tg4 + 2);

    // Drain all VMEM; fence so no consumer hoists above the wait (rule 18).
    asm volatile("s_waitcnt vmcnt(0)" ::: "memory");
    __builtin_amdgcn_sched_barrier(0);

    float ww[4]  = {w4.x, w4.y, w4.z, w4.w};
    float tg[12] = {t0.x, t0.y, t0.z, t0.w,
                    t1.x, t1.y, t1.z, t1.w,
                    t2.x, t2.y, t2.z, t2.w};
    fvec4 pa[4] = {pa0, pa1, pa2, pa3};
    fvec4 pb[4] = {pb0, pb1, pb2, pb3};
    fvec4 pp[4] = {pp0, pp1, pp2, pp3};

    float res[12];
#pragma unroll
    for (int k = 0; k < 4; ++k) {
        float qx = pb[k].x, qy = pb[k].y, qz = pb[k].z, qw = pa[k].w;
        float px = pp[k].x, py = pp[k].y, pz = pp[k].z;

        // uv = cross(qv, pts)
        float ux = qy*pz - qz*py;
        float uy = qz*px - qx*pz;
        float uz = qx*py - qy*px;
        // cross(qv, uv)
        float cx = qy*uz - qz*uy;
        float cy = qz*ux - qx*uz;
        float cz = qx*uy - qy*ux;
        // rotated = pts + 2*(qw*uv + cross(qv,uv)) + t   (q pre-normalized)
        float rx = px + 2.0f*(qw*ux + cx) + pa[k].x;
        float ry = py + 2.0f*(qw*uy + cy) + pa[k].y;
        float rz = pz + 2.0f*(qw*uz + cz) + pa[k].z;

        // cart2polar (matches reference)
        float rho = sqrtf(rx*rx + ry*ry);
        float r   = sqrtf(rho*rho + rz*rz);
        float az  = atan2f(ry, rx);
        float el  = atan2f(rz, rho);

        res[k*3 + 0] = (r  - tg[k*3 + 0]) * ww[k];
        res[k*3 + 1] = (az - tg[k*3 + 1]) * ww[k];
        res[k*3 + 2] = (el - tg[k*3 + 2]) * ww[k];
    }

    fvec4* o4 = reinterpret_cast<fvec4*>(out) + (size_t)i4 * 3;
    __builtin_nontemporal_store((fvec4){res[0], res[1], res[2],  res[3]},  o4 + 0);
    __builtin_nontemporal_store((fvec4){res[4], res[5], res[6],  res[7]},  o4 + 1);
    __builtin_nontemporal_store((fvec4){res[8], res[9], res[10], res[11]}, o4 + 2);
}

// Fallback path: direct global gathers (no ws needed).
__global__ __launch_bounds__(256) void ba_fallback_kernel(
    const float* __restrict__ poses, const float* __restrict__ patch_coords,
    const float* __restrict__ elev, const int* __restrict__ poses_idx,
    const int* __restrict__ patch_idx, const float* __restrict__ target,
    const float* __restrict__ weights, float* __restrict__ out, int n)
{
    int i = blockIdx.x * blockDim.x + threadIdx.x;
    if (i >= n) return;
    int pi = poses_idx[i];
    int qi = patch_idx[i];
    const float* p = poses + (size_t)pi * 7;
    float tx = p[0], ty = p[1], tz = p[2];
    float qx = p[3], qy = p[4], qz = p[5], qw = p[6];
    float inv = rsqrtf(qx*qx + qy*qy + qz*qz + qw*qw);
    qx *= inv; qy *= inv; qz *= inv; qw *= inv;
    float2 pc = *reinterpret_cast<const float2*>(patch_coords + (size_t)qi * 2);
    float px = pc.x, py = pc.y, pz = elev[qi];
    float ux = qy*pz - qz*py, uy = qz*px - qx*pz, uz = qx*py - qy*px;
    float cx = qy*uz - qz*uy, cy = qz*ux - qx*uz, cz = qx*uy - qy*ux;
    float rx = px + 2.0f*(qw*ux + cx) + tx;
    float ry = py + 2.0f*(qw*uy + cy) + ty;
    float rz = pz + 2.0f*(qw*uz + cz) + tz;
    float rho = sqrtf(rx*rx + ry*ry);
    float r   = sqrtf(rho*rho + rz*rz);
    float az  = atan2f(ry, rx);
    float el  = atan2f(rz, rho);
    float w = weights[i];
    out[(size_t)i*3+0] = (r  - target[(size_t)i*3+0]) * w;
    out[(size_t)i*3+1] = (az - target[(size_t)i*3+1]) * w;
    out[(size_t)i*3+2] = (el - target[(size_t)i*3+2]) * w;
}

extern "C" void kernel_launch(void* const* d_in, const int* in_sizes, int n_in,
                              void* d_out, int out_size, void* d_ws, size_t ws_size,
                              hipStream_t stream) {
    const float* poses        = (const float*)d_in[0];
    const float* patch_coords = (const float*)d_in[1];
    const float* elev         = (const float*)d_in[2];
    const int*   poses_idx    = (const int*)d_in[3];
    const int*   patch_idx    = (const int*)d_in[4];
    const float* target       = (const float*)d_in[5];
    const float* weights      = (const float*)d_in[6];
    float*       out          = (float*)d_out;

    int n  = in_sizes[3];  // NUM_OBS (2097152, divisible by 4)
    int n4 = n / 4;

    size_t patch_bytes = (size_t)NPATCHES * 16;  // 4 MiB
    size_t pose_bytes  = (size_t)NPOSES * 32;    // 128 KiB

    if (ws_size >= patch_bytes + pose_bytes) {
        fvec4* patch4 = (fvec4*)d_ws;
        fvec4* pose4  = (fvec4*)((char*)d_ws + patch_bytes);

        pack_poses_kernel<<<(NPOSES + 255) / 256, 256, 0, stream>>>(poses, pose4, NPOSES);
        pack_patches_kernel<<<(NPATCHES + 255) / 256, 256, 0, stream>>>(
            patch_coords, elev, patch4, NPATCHES);

        ba_main_kernel<<<(n4 + 255) / 256, 256, 0, stream>>>(
            pose4, patch4, poses_idx, patch_idx, target, weights, out, n4);
    } else {
        ba_fallback_kernel<<<(n + 255) / 256, 256, 0, stream>>>(
            poses, patch_coords, elev, poses_idx, patch_idx, target, weights, out, n);
    }
}